// Round 1
// baseline (5810.335 us; speedup 1.0000x reference)
//
#include <hip/hip_runtime.h>
#include <hip/hip_bf16.h>
#include <math.h>

#define BB   64
#define SS   256
#define HH   512
#define HD2  1024   // 2H
#define EE   256
#define VV   32000
#define MLSZ 32256
#define G3   1536   // 3H

// ---------- helpers ----------
__device__ __forceinline__ float wredsum(float v) {
#pragma unroll
  for (int o = 32; o > 0; o >>= 1) v += __shfl_down(v, o);
  return v;
}
__device__ __forceinline__ float wredmax(float v) {
#pragma unroll
  for (int o = 32; o > 0; o >>= 1) v = fmaxf(v, __shfl_down(v, o));
  return v;
}
__device__ __forceinline__ float ftanh(float x) {
  float e = __expf(-2.f * fabsf(x));
  float t = (1.f - e) / (1.f + e);
  return copysignf(t, x);
}
__device__ __forceinline__ float fsigmoid(float x) { return 1.f / (1.f + __expf(-x)); }
__device__ __forceinline__ float dot4(float4 a, float4 b) {
  return a.x*b.x + a.y*b.y + a.z*b.z + a.w*b.w;
}

// ---------- generic small GEMM: C[64,N] = A[64,K] @ W[N,K]^T (+bias), atomic accum ----------
// grid (N/64, ksplits); 256 thr. klen multiple of 32. C must be zero-initialized.
__global__ __launch_bounds__(256) void k_smallgemm(
    const float* __restrict__ A, int lda,
    const float* __restrict__ W, int ldw,
    const float* __restrict__ bias,
    float* __restrict__ C, int ldc, int klen)
{
  __shared__ float As[64][36];
  __shared__ float Ws[64][36];
  const int tid = threadIdx.x;
  const int n0 = blockIdx.x * 64;
  const int kbeg = blockIdx.y * klen;
  const int tb = tid & 15;   // rows tb+16i
  const int tn = tid >> 4;   // cols tn+16j
  float acc[4][4];
#pragma unroll
  for (int i = 0; i < 4; ++i)
#pragma unroll
    for (int j = 0; j < 4; ++j)
      acc[i][j] = (blockIdx.y == 0) ? bias[n0 + tn + 16*j] : 0.f;

  const int rr = tid >> 3;
  const int cc = (tid & 7) * 4;
  for (int kc = kbeg; kc < kbeg + klen; kc += 32) {
    __syncthreads();
#pragma unroll
    for (int r = rr; r < 64; r += 32) {
      *(float4*)&As[r][cc] = *(const float4*)&A[(size_t)r * lda + kc + cc];
      *(float4*)&Ws[r][cc] = *(const float4*)&W[(size_t)(n0 + r) * ldw + kc + cc];
    }
    __syncthreads();
#pragma unroll
    for (int k4 = 0; k4 < 32; k4 += 4) {
      float4 a[4], w[4];
#pragma unroll
      for (int i = 0; i < 4; ++i) a[i] = *(const float4*)&As[tb + 16*i][k4];
#pragma unroll
      for (int j = 0; j < 4; ++j) w[j] = *(const float4*)&Ws[tn + 16*j][k4];
#pragma unroll
      for (int i = 0; i < 4; ++i)
#pragma unroll
        for (int j = 0; j < 4; ++j)
          acc[i][j] += dot4(a[i], w[j]);
    }
  }
#pragma unroll
  for (int i = 0; i < 4; ++i)
#pragma unroll
    for (int j = 0; j < 4; ++j)
      atomicAdd(&C[(size_t)(tb + 16*i) * ldc + n0 + tn + 16*j], acc[i][j]);
}

// ---------- pass1: attn_scores + select_reading over one enc scan ----------
// grid 256 = (b:64, schunk:4); 256 thr. selread zero-initialized.
__global__ __launch_bounds__(256) void k_pass1(
    const float* __restrict__ enc, const float* __restrict__ astr,
    const int* __restrict__ seq, const int* __restrict__ iidx,
    const float* __restrict__ ppc,
    float* __restrict__ scores, float* __restrict__ selread)
{
  const int b  = blockIdx.x >> 2;
  const int sc = blockIdx.x & 3;
  const int tid = threadIdx.x;
  const int lane = tid & 63;
  const int w = tid >> 6;
  __shared__ float sr_s[4][1024];

  const int d0 = lane * 16;
  const float* ap = astr + (size_t)b * HD2 + d0;
  const float4 a0 = *(const float4*)(ap + 0);
  const float4 a1 = *(const float4*)(ap + 4);
  const float4 a2 = *(const float4*)(ap + 8);
  const float4 a3 = *(const float4*)(ap + 12);

  float sr[16];
#pragma unroll
  for (int j = 0; j < 16; ++j) sr[j] = 0.f;

  const int idxb = iidx[b];
  const int sbase = sc * 64 + w * 16;
  for (int si = 0; si < 16; ++si) {
    const int s = sbase + si;
    const float* row = enc + ((size_t)b * SS + s) * HD2 + d0;
    const float4 q0 = *(const float4*)(row + 0);
    const float4 q1 = *(const float4*)(row + 4);
    const float4 q2 = *(const float4*)(row + 8);
    const float4 q3 = *(const float4*)(row + 12);
    float dot = dot4(q0, a0) + dot4(q1, a1) + dot4(q2, a2) + dot4(q3, a3);
    dot = wredsum(dot);
    if (lane == 0) scores[b * SS + s] = dot;
    const float sw = (seq[b * SS + s] == idxb) ? ppc[b * SS + s] : 0.f;
    if (sw != 0.f) {   // wave-uniform branch; matches are rare
      sr[0]  += sw * q0.x; sr[1]  += sw * q0.y; sr[2]  += sw * q0.z; sr[3]  += sw * q0.w;
      sr[4]  += sw * q1.x; sr[5]  += sw * q1.y; sr[6]  += sw * q1.z; sr[7]  += sw * q1.w;
      sr[8]  += sw * q2.x; sr[9]  += sw * q2.y; sr[10] += sw * q2.z; sr[11] += sw * q2.w;
      sr[12] += sw * q3.x; sr[13] += sw * q3.y; sr[14] += sw * q3.z; sr[15] += sw * q3.w;
    }
  }
#pragma unroll
  for (int j = 0; j < 16; ++j) sr_s[w][d0 + j] = sr[j];
  __syncthreads();
#pragma unroll
  for (int j = 0; j < 4; ++j) {
    const int d = tid * 4 + j;
    const float v = sr_s[0][d] + sr_s[1][d] + sr_s[2][d] + sr_s[3][d];
    atomicAdd(&selread[(size_t)b * HD2 + d], v);
  }
}

// ---------- softmax over S per row ----------
__global__ __launch_bounds__(256) void k_softmax_s(float* __restrict__ scores)
{
  const int b = blockIdx.x;
  const int tid = threadIdx.x;
  const int lane = tid & 63, w = tid >> 6;
  __shared__ float red[4];
  __shared__ float bm, bsum;
  float x = scores[b * SS + tid];
  float m = wredmax(x);
  if (lane == 0) red[w] = m;
  __syncthreads();
  if (tid == 0) bm = fmaxf(fmaxf(red[0], red[1]), fmaxf(red[2], red[3]));
  __syncthreads();
  float e = __expf(x - bm);
  float s = wredsum(e);
  if (lane == 0) red[w] = s;
  __syncthreads();
  if (tid == 0) bsum = red[0] + red[1] + red[2] + red[3];
  __syncthreads();
  scores[b * SS + tid] = e / bsum;
}

// ---------- pass2: context = sum_s w[b,s]*enc[b,s,:] ----------
__global__ __launch_bounds__(256) void k_pass2(
    const float* __restrict__ enc, const float* __restrict__ wgt,
    float* __restrict__ context)
{
  const int b  = blockIdx.x >> 2;
  const int sc = blockIdx.x & 3;
  const int tid = threadIdx.x;
  const int lane = tid & 63;
  const int w = tid >> 6;
  __shared__ float cs[4][1024];
  const int d0 = lane * 16;
  float a[16];
#pragma unroll
  for (int j = 0; j < 16; ++j) a[j] = 0.f;
  const int sbase = sc * 64 + w * 16;
  for (int si = 0; si < 16; ++si) {
    const int s = sbase + si;
    const float wt = wgt[b * SS + s];
    const float* row = enc + ((size_t)b * SS + s) * HD2 + d0;
    const float4 q0 = *(const float4*)(row + 0);
    const float4 q1 = *(const float4*)(row + 4);
    const float4 q2 = *(const float4*)(row + 8);
    const float4 q3 = *(const float4*)(row + 12);
    a[0]  += wt * q0.x; a[1]  += wt * q0.y; a[2]  += wt * q0.z; a[3]  += wt * q0.w;
    a[4]  += wt * q1.x; a[5]  += wt * q1.y; a[6]  += wt * q1.z; a[7]  += wt * q1.w;
    a[8]  += wt * q2.x; a[9]  += wt * q2.y; a[10] += wt * q2.z; a[11] += wt * q2.w;
    a[12] += wt * q3.x; a[13] += wt * q3.y; a[14] += wt * q3.z; a[15] += wt * q3.w;
  }
#pragma unroll
  for (int j = 0; j < 16; ++j) cs[w][d0 + j] = a[j];
  __syncthreads();
#pragma unroll
  for (int j = 0; j < 4; ++j) {
    const int d = tid * 4 + j;
    atomicAdd(&context[(size_t)b * HD2 + d],
              cs[0][d] + cs[1][d] + cs[2][d] + cs[3][d]);
  }
}

// ---------- build cat1=[context,embedding]; copy select_reading into x ----------
__global__ __launch_bounds__(256) void k_cat1(
    const float* __restrict__ context, const float* __restrict__ embed,
    const int* __restrict__ iidx, const float* __restrict__ selread,
    float* __restrict__ cat1, float* __restrict__ xbuf)
{
  const int b = blockIdx.x;
  const int tid = threadIdx.x;
  for (int d = tid; d < HD2; d += 256) {
    cat1[(size_t)b * 1280 + d] = context[(size_t)b * HD2 + d];
    xbuf[(size_t)b * G3 + 512 + d] = selread[(size_t)b * HD2 + d];
  }
  int ei = iidx[b];
  if (ei >= VV) ei = 2;
  cat1[(size_t)b * 1280 + 1024 + tid] = embed[(size_t)ei * EE + tid];
}

// ---------- GRU cell ----------
__global__ __launch_bounds__(256) void k_gru(
    const float* __restrict__ gi, const float* __restrict__ gh,
    const float* __restrict__ ps, float* __restrict__ st)
{
  const int t = blockIdx.x * 256 + threadIdx.x;   // B*H
  const int b = t >> 9, h = t & 511;
  const float* gib = gi + (size_t)b * G3;
  const float* ghb = gh + (size_t)b * G3;
  const float r = fsigmoid(gib[h] + ghb[h]);
  const float z = fsigmoid(gib[512 + h] + ghb[512 + h]);
  const float n = ftanh(gib[1024 + h] + r * ghb[1024 + h]);
  st[t] = (1.f - z) * n + z * ps[t];
}

// ---------- score_g = state @ W_o^T + b_o  (64 x 32000, K=512) ----------
// grid 125; tile 64x256; micro 8x8; along-K float4 LDS reads.
__global__ __launch_bounds__(256, 2) void k_score_g(
    const float* __restrict__ st, const float* __restrict__ Wo,
    const float* __restrict__ bo, float* __restrict__ sg)
{
  __shared__ float Ss[64][36];
  __shared__ float Ws[256][36];
  const int tid = threadIdx.x;
  const int n0 = blockIdx.x * 256;
  const int tb = tid & 7;    // rows tb+8i
  const int tn = tid >> 3;   // cols tn+32j
  float acc[8][8];
#pragma unroll
  for (int i = 0; i < 8; ++i)
#pragma unroll
    for (int j = 0; j < 8; ++j) acc[i][j] = 0.f;

  const int rr = tid >> 3;
  const int cc = (tid & 7) * 4;
  for (int kc = 0; kc < 512; kc += 32) {
    __syncthreads();
#pragma unroll
    for (int r = rr; r < 64; r += 32)
      *(float4*)&Ss[r][cc] = *(const float4*)&st[(size_t)r * 512 + kc + cc];
#pragma unroll
    for (int r = rr; r < 256; r += 32)
      *(float4*)&Ws[r][cc] = *(const float4*)&Wo[(size_t)(n0 + r) * 512 + kc + cc];
    __syncthreads();
#pragma unroll
    for (int k4 = 0; k4 < 32; k4 += 4) {
      float4 a[8], w[8];
#pragma unroll
      for (int i = 0; i < 8; ++i) a[i] = *(const float4*)&Ss[tb + 8*i][k4];
#pragma unroll
      for (int j = 0; j < 8; ++j) w[j] = *(const float4*)&Ws[tn + 32*j][k4];
#pragma unroll
      for (int i = 0; i < 8; ++i)
#pragma unroll
        for (int j = 0; j < 8; ++j)
          acc[i][j] += dot4(a[i], w[j]);
    }
  }
#pragma unroll
  for (int i = 0; i < 8; ++i)
#pragma unroll
    for (int j = 0; j < 8; ++j)
      sg[(size_t)(tb + 8*i) * VV + n0 + tn + 32*j] = acc[i][j] + bo[n0 + tn + 32*j];
}

// ---------- fused score_c: scc[b,s] = sum_h tanh(enc[b,s,:]@Wc[h,:]+bc[h]) * state[b,h] ----------
// grid (128 Mtiles, 4 Ntiles); tile 128x128; micro 8x8 along-K. scc zero-initialized.
__global__ __launch_bounds__(256, 2) void k_score_c(
    const float* __restrict__ enc, const float* __restrict__ Wc,
    const float* __restrict__ bc, const float* __restrict__ st,
    float* __restrict__ scc)
{
  __shared__ float As[128][36];
  __shared__ float Ws[128][36];
  __shared__ float part[16][128];
  const int tid = threadIdx.x;
  const int m0 = blockIdx.x * 128;
  const int n0 = blockIdx.y * 128;
  const int b = m0 >> 8;           // tile stays within one batch row
  const int tb = tid & 15;         // rows tb+16i  (i<8)
  const int tn = tid >> 4;         // cols tn+16j  (j<8)
  float acc[8][8];
#pragma unroll
  for (int i = 0; i < 8; ++i)
#pragma unroll
    for (int j = 0; j < 8; ++j) acc[i][j] = 0.f;

  const int rr = tid >> 3;
  const int cc = (tid & 7) * 4;
  for (int kc = 0; kc < 1024; kc += 32) {
    __syncthreads();
#pragma unroll
    for (int r = rr; r < 128; r += 32) {
      *(float4*)&As[r][cc] = *(const float4*)&enc[((size_t)m0 + r) * HD2 + kc + cc];
      *(float4*)&Ws[r][cc] = *(const float4*)&Wc[((size_t)n0 + r) * HD2 + kc + cc];
    }
    __syncthreads();
#pragma unroll
    for (int k4 = 0; k4 < 32; k4 += 4) {
      float4 a[8], w[8];
#pragma unroll
      for (int i = 0; i < 8; ++i) a[i] = *(const float4*)&As[tb + 16*i][k4];
#pragma unroll
      for (int j = 0; j < 8; ++j) w[j] = *(const float4*)&Ws[tn + 16*j][k4];
#pragma unroll
      for (int i = 0; i < 8; ++i)
#pragma unroll
        for (int j = 0; j < 8; ++j)
          acc[i][j] += dot4(a[i], w[j]);
    }
  }
  // epilogue: tanh, weight by state, reduce over h
  float stv[8];
#pragma unroll
  for (int j = 0; j < 8; ++j) stv[j] = st[(size_t)b * 512 + n0 + tn + 16*j];
#pragma unroll
  for (int i = 0; i < 8; ++i) {
    float p = 0.f;
#pragma unroll
    for (int j = 0; j < 8; ++j)
      p += ftanh(acc[i][j] + bc[n0 + tn + 16*j]) * stv[j];
    part[tn][tb + 16*i] = p;
  }
  __syncthreads();
  if (tid < 128) {
    float s = 0.f;
#pragma unroll
    for (int t = 0; t < 16; ++t) s += part[t][tid];
    atomicAdd(&scc[b * SS + (m0 & 255) + tid], s);
  }
}

// ---------- softmax over [score_g | score_c] (32256); writes prob_g to out, prob_c0, stats ----------
__global__ __launch_bounds__(1024) void k_bigsoftmax(
    const float* __restrict__ sg, const float* __restrict__ scc,
    float* __restrict__ out, float* __restrict__ pc0, float* __restrict__ stats)
{
  const int b = blockIdx.x;
  const int tid = threadIdx.x;
  const int lane = tid & 63, w = tid >> 6;
  __shared__ float red[16];
  __shared__ float bm, bsum;
  const float* sgb = sg + (size_t)b * VV;
  const float* scb = scc + (size_t)b * SS;

  float m = -3.0e38f;
  for (int v = tid; v < VV; v += 1024) m = fmaxf(m, sgb[v]);
  if (tid < SS) m = fmaxf(m, scb[tid]);
  m = wredmax(m);
  if (lane == 0) red[w] = m;
  __syncthreads();
  if (tid == 0) {
    float t = red[0];
    for (int i = 1; i < 16; ++i) t = fmaxf(t, red[i]);
    bm = t;
  }
  __syncthreads();
  const float mx = bm;

  float s = 0.f;
  for (int v = tid; v < VV; v += 1024) s += __expf(sgb[v] - mx);
  if (tid < SS) s += __expf(scb[tid] - mx);
  s = wredsum(s);
  if (lane == 0) red[w] = s;
  __syncthreads();
  if (tid == 0) {
    float t = 0.f;
    for (int i = 0; i < 16; ++i) t += red[i];
    bsum = t;
  }
  __syncthreads();
  const float inv = 1.f / bsum;
  if (tid == 0) { stats[2*b] = mx; stats[2*b + 1] = inv; }

  float* outb = out + (size_t)b * MLSZ;
  for (int v = tid; v < VV; v += 1024) outb[v] = __expf(sgb[v] - mx) * inv;
  if (tid < SS) {
    pc0[b * SS + tid] = __expf(scb[tid] - mx) * inv;
    outb[VV + tid] = 0.f;   // tail region; scatter overwrites selected spots
  }
}

// ---------- prob_c[b,j] = sum_i pc0[b,i] * (seq[b,i]==seq[b,j]) ----------
__global__ __launch_bounds__(256) void k_probc(
    const int* __restrict__ seq, const float* __restrict__ pc0,
    float* __restrict__ pcout)
{
  const int b = blockIdx.x;
  const int tid = threadIdx.x;
  __shared__ int sq[256];
  __shared__ float pp[256];
  sq[tid] = seq[b * SS + tid];
  pp[tid] = pc0[b * SS + tid];
  __syncthreads();
  const int mys = sq[tid];
  float acc = 0.f;
  for (int i = 0; i < 256; ++i) acc += (sq[i] == mys) ? pp[i] : 0.f;
  pcout[b * SS + tid] = acc;
}

// ---------- scatter: out[b, seq[b,j]] = prob_c[b,j] + (v<V ? prob_g[b,v] : 0) ----------
// prob_g is recomputed from saved (mx, inv) so no read-after-write race on duplicates.
__global__ __launch_bounds__(256) void k_scatter(
    const int* __restrict__ seq, const float* __restrict__ pcout,
    const float* __restrict__ sg, const float* __restrict__ stats,
    float* __restrict__ out)
{
  const int b = blockIdx.x;
  const int tid = threadIdx.x;
  const int v = seq[b * SS + tid];
  if (v < 0 || v >= MLSZ) return;   // 'drop' semantics
  float val = pcout[b * SS + tid];
  if (v < VV) val += __expf(sg[(size_t)b * VV + v] - stats[2*b]) * stats[2*b + 1];
  out[(size_t)b * MLSZ + v] = val;  // duplicates write identical values
}

// ---------- launch ----------
extern "C" void kernel_launch(void* const* d_in, const int* in_sizes, int n_in,
                              void* d_out, int out_size, void* d_ws, size_t ws_size,
                              hipStream_t stream)
{
  (void)in_sizes; (void)n_in; (void)out_size; (void)ws_size;
  const int*   input_idx = (const int*)d_in[0];
  const float* enc       = (const float*)d_in[1];
  const int*   seq       = (const int*)d_in[2];
  const float* pre_state = (const float*)d_in[3];
  const float* ppc       = (const float*)d_in[4];
  const float* embed     = (const float*)d_in[5];
  const float* W_aw = (const float*)d_in[6];  const float* b_aw = (const float*)d_in[7];
  const float* W_ac = (const float*)d_in[8];  const float* b_ac = (const float*)d_in[9];
  const float* W_ih = (const float*)d_in[10]; const float* b_ih = (const float*)d_in[11];
  const float* W_hh = (const float*)d_in[12]; const float* b_hh = (const float*)d_in[13];
  const float* W_o  = (const float*)d_in[14]; const float* b_o  = (const float*)d_in[15];
  const float* W_c  = (const float*)d_in[16]; const float* b_c  = (const float*)d_in[17];

  float* out   = (float*)d_out;
  float* st    = out + (size_t)BB * MLSZ;   // state output
  float* pcout = st + BB * HH;              // prob_c output

  // workspace layout (floats). First region is atomically accumulated -> one memset.
  float* ws      = (float*)d_ws;
  float* astr    = ws;                   // 64*1024
  float* gh      = astr    + 65536;      // 64*1536
  float* xbuf    = gh      + 98304;      // 64*1536
  float* gi      = xbuf    + 98304;      // 64*1536
  float* selread = gi      + 98304;      // 64*1024
  float* context = selread + 65536;      // 64*1024
  float* scc     = context + 65536;      // 64*256
  const size_t zlen = 65536 + 98304 + 98304 + 98304 + 65536 + 65536 + 16384; // 507904
  float* scores  = scc     + 16384;      // 64*256
  float* cat1    = scores  + 16384;      // 64*1280
  float* sg      = cat1    + 81920;      // 64*32000
  float* pc0     = sg      + 2048000;    // 64*256
  float* stats   = pc0     + 16384;      // 128

  hipMemsetAsync(ws, 0, zlen * sizeof(float), stream);

  // attn_strength = pre_state @ W_aw^T + b_aw ; gh = pre_state @ W_hh^T + b_hh
  k_smallgemm<<<dim3(16, 2), 256, 0, stream>>>(pre_state, 512, W_aw, 512, b_aw, astr, 1024, 256);
  k_smallgemm<<<dim3(24, 2), 256, 0, stream>>>(pre_state, 512, W_hh, 512, b_hh, gh, 1536, 256);
  // enc scan #1: attn_scores + select_reading
  k_pass1<<<256, 256, 0, stream>>>(enc, astr, seq, input_idx, ppc, scores, selread);
  k_softmax_s<<<64, 256, 0, stream>>>(scores);
  // enc scan #2: context
  k_pass2<<<256, 256, 0, stream>>>(enc, scores, context);
  // concat buffers
  k_cat1<<<64, 256, 0, stream>>>(context, embed, input_idx, selread, cat1, xbuf);
  // attn_reading -> x[:, :512] ; gi = x @ W_ih^T + b_ih
  k_smallgemm<<<dim3(8, 2), 256, 0, stream>>>(cat1, 1280, W_ac, 1280, b_ac, xbuf, 1536, 640);
  k_smallgemm<<<dim3(24, 4), 256, 0, stream>>>(xbuf, 1536, W_ih, 1536, b_ih, gi, 1536, 384);
  // GRU -> state (written straight into d_out)
  k_gru<<<128, 256, 0, stream>>>(gi, gh, pre_state, st);
  // output scores
  k_score_g<<<125, 256, 0, stream>>>(st, W_o, b_o, sg);
  k_score_c<<<dim3(128, 4), 256, 0, stream>>>(enc, W_c, b_c, st, scc);
  // softmax over 32256, prob_c aggregation, scatter-assemble out
  k_bigsoftmax<<<64, 1024, 0, stream>>>(sg, scc, out, pc0, stats);
  k_probc<<<64, 256, 0, stream>>>(seq, pc0, pcout);
  k_scatter<<<64, 256, 0, stream>>>(seq, pcout, sg, stats, out);
}

// Round 2
// 542.769 us; speedup vs baseline: 10.7050x; 10.7050x over previous
//
#include <hip/hip_runtime.h>
#include <hip/hip_bf16.h>
#include <math.h>

#define BB   64
#define SS   256
#define HH   512
#define HD2  1024   // 2H
#define EE   256
#define VV   32000
#define MLSZ 32256
#define G3   1536   // 3H

typedef __attribute__((ext_vector_type(8))) short bhalf8;
typedef __attribute__((ext_vector_type(4))) float f32x4;

// ---------- helpers ----------
__device__ __forceinline__ float wredsum(float v) {
#pragma unroll
  for (int o = 32; o > 0; o >>= 1) v += __shfl_down(v, o);
  return v;
}
__device__ __forceinline__ float wredmax(float v) {
#pragma unroll
  for (int o = 32; o > 0; o >>= 1) v = fmaxf(v, __shfl_down(v, o));
  return v;
}
__device__ __forceinline__ float ftanh(float x) {
  float e = __expf(-2.f * fabsf(x));
  float t = (1.f - e) / (1.f + e);
  return copysignf(t, x);
}
__device__ __forceinline__ float fsigmoid(float x) { return 1.f / (1.f + __expf(-x)); }
__device__ __forceinline__ float dot4(float4 a, float4 b) {
  return a.x*b.x + a.y*b.y + a.z*b.z + a.w*b.w;
}
// fp32 -> bf16 hi/lo split (RNE both): x ~= hi + lo to ~2^-18 rel
__device__ __forceinline__ void split2(float x, ushort& h, ushort& l) {
  uint u = __float_as_uint(x);
  uint hr = (u + 0x7fffu + ((u >> 16) & 1u)) & 0xffff0000u;
  h = (ushort)(hr >> 16);
  float r = x - __uint_as_float(hr);
  uint u2 = __float_as_uint(r);
  l = (ushort)((u2 + 0x7fffu + ((u2 >> 16) & 1u)) >> 16);
}

// ---------- split fp32 array into bf16 hi/lo arrays ----------
__global__ __launch_bounds__(256) void k_split(
    const float* __restrict__ x, ushort* __restrict__ hi, ushort* __restrict__ lo)
{
  const int i = (blockIdx.x * 256 + threadIdx.x) * 4;
  const float4 v = *(const float4*)&x[i];
  ushort4 h, l;
  split2(v.x, h.x, l.x); split2(v.y, h.y, l.y);
  split2(v.z, h.z, l.z); split2(v.w, h.w, l.w);
  *(ushort4*)&hi[i] = h;
  *(ushort4*)&lo[i] = l;
}

// ---------- generic small GEMM: C[64,N] = A[64,K] @ W[N,K]^T (+bias), atomic accum ----------
__global__ __launch_bounds__(256) void k_smallgemm(
    const float* __restrict__ A, int lda,
    const float* __restrict__ W, int ldw,
    const float* __restrict__ bias,
    float* __restrict__ C, int ldc, int klen)
{
  __shared__ float As[64][36];
  __shared__ float Ws[64][36];
  const int tid = threadIdx.x;
  const int n0 = blockIdx.x * 64;
  const int kbeg = blockIdx.y * klen;
  const int tb = tid & 15;
  const int tn = tid >> 4;
  float acc[4][4];
#pragma unroll
  for (int i = 0; i < 4; ++i)
#pragma unroll
    for (int j = 0; j < 4; ++j)
      acc[i][j] = (blockIdx.y == 0) ? bias[n0 + tn + 16*j] : 0.f;

  const int rr = tid >> 3;
  const int cc = (tid & 7) * 4;
  for (int kc = kbeg; kc < kbeg + klen; kc += 32) {
    __syncthreads();
#pragma unroll
    for (int r = rr; r < 64; r += 32) {
      *(float4*)&As[r][cc] = *(const float4*)&A[(size_t)r * lda + kc + cc];
      *(float4*)&Ws[r][cc] = *(const float4*)&W[(size_t)(n0 + r) * ldw + kc + cc];
    }
    __syncthreads();
#pragma unroll
    for (int k4 = 0; k4 < 32; k4 += 4) {
      float4 a[4], w[4];
#pragma unroll
      for (int i = 0; i < 4; ++i) a[i] = *(const float4*)&As[tb + 16*i][k4];
#pragma unroll
      for (int j = 0; j < 4; ++j) w[j] = *(const float4*)&Ws[tn + 16*j][k4];
#pragma unroll
      for (int i = 0; i < 4; ++i)
#pragma unroll
        for (int j = 0; j < 4; ++j)
          acc[i][j] += dot4(a[i], w[j]);
    }
  }
#pragma unroll
  for (int i = 0; i < 4; ++i)
#pragma unroll
    for (int j = 0; j < 4; ++j)
      atomicAdd(&C[(size_t)(tb + 16*i) * ldc + n0 + tn + 16*j], acc[i][j]);
}

// ---------- pass1: attn_scores + select_reading ----------
__global__ __launch_bounds__(256) void k_pass1(
    const float* __restrict__ enc, const float* __restrict__ astr,
    const int* __restrict__ seq, const int* __restrict__ iidx,
    const float* __restrict__ ppc,
    float* __restrict__ scores, float* __restrict__ selread)
{
  const int b  = blockIdx.x >> 2;
  const int sc = blockIdx.x & 3;
  const int tid = threadIdx.x;
  const int lane = tid & 63;
  const int w = tid >> 6;
  __shared__ float sr_s[4][1024];

  const int d0 = lane * 16;
  const float* ap = astr + (size_t)b * HD2 + d0;
  const float4 a0 = *(const float4*)(ap + 0);
  const float4 a1 = *(const float4*)(ap + 4);
  const float4 a2 = *(const float4*)(ap + 8);
  const float4 a3 = *(const float4*)(ap + 12);

  float sr[16];
#pragma unroll
  for (int j = 0; j < 16; ++j) sr[j] = 0.f;

  const int idxb = iidx[b];
  const int sbase = sc * 64 + w * 16;
  for (int si = 0; si < 16; ++si) {
    const int s = sbase + si;
    const float* row = enc + ((size_t)b * SS + s) * HD2 + d0;
    const float4 q0 = *(const float4*)(row + 0);
    const float4 q1 = *(const float4*)(row + 4);
    const float4 q2 = *(const float4*)(row + 8);
    const float4 q3 = *(const float4*)(row + 12);
    float dot = dot4(q0, a0) + dot4(q1, a1) + dot4(q2, a2) + dot4(q3, a3);
    dot = wredsum(dot);
    if (lane == 0) scores[b * SS + s] = dot;
    const float sw = (seq[b * SS + s] == idxb) ? ppc[b * SS + s] : 0.f;
    if (sw != 0.f) {
      sr[0]  += sw * q0.x; sr[1]  += sw * q0.y; sr[2]  += sw * q0.z; sr[3]  += sw * q0.w;
      sr[4]  += sw * q1.x; sr[5]  += sw * q1.y; sr[6]  += sw * q1.z; sr[7]  += sw * q1.w;
      sr[8]  += sw * q2.x; sr[9]  += sw * q2.y; sr[10] += sw * q2.z; sr[11] += sw * q2.w;
      sr[12] += sw * q3.x; sr[13] += sw * q3.y; sr[14] += sw * q3.z; sr[15] += sw * q3.w;
    }
  }
#pragma unroll
  for (int j = 0; j < 16; ++j) sr_s[w][d0 + j] = sr[j];
  __syncthreads();
#pragma unroll
  for (int j = 0; j < 4; ++j) {
    const int d = tid * 4 + j;
    const float v = sr_s[0][d] + sr_s[1][d] + sr_s[2][d] + sr_s[3][d];
    atomicAdd(&selread[(size_t)b * HD2 + d], v);
  }
}

// ---------- softmax over S per row ----------
__global__ __launch_bounds__(256) void k_softmax_s(float* __restrict__ scores)
{
  const int b = blockIdx.x;
  const int tid = threadIdx.x;
  const int lane = tid & 63, w = tid >> 6;
  __shared__ float red[4];
  __shared__ float bm, bsum;
  float x = scores[b * SS + tid];
  float m = wredmax(x);
  if (lane == 0) red[w] = m;
  __syncthreads();
  if (tid == 0) bm = fmaxf(fmaxf(red[0], red[1]), fmaxf(red[2], red[3]));
  __syncthreads();
  float e = __expf(x - bm);
  float s = wredsum(e);
  if (lane == 0) red[w] = s;
  __syncthreads();
  if (tid == 0) bsum = red[0] + red[1] + red[2] + red[3];
  __syncthreads();
  scores[b * SS + tid] = e / bsum;
}

// ---------- pass2: context ----------
__global__ __launch_bounds__(256) void k_pass2(
    const float* __restrict__ enc, const float* __restrict__ wgt,
    float* __restrict__ context)
{
  const int b  = blockIdx.x >> 2;
  const int sc = blockIdx.x & 3;
  const int tid = threadIdx.x;
  const int lane = tid & 63;
  const int w = tid >> 6;
  __shared__ float cs[4][1024];
  const int d0 = lane * 16;
  float a[16];
#pragma unroll
  for (int j = 0; j < 16; ++j) a[j] = 0.f;
  const int sbase = sc * 64 + w * 16;
  for (int si = 0; si < 16; ++si) {
    const int s = sbase + si;
    const float wt = wgt[b * SS + s];
    const float* row = enc + ((size_t)b * SS + s) * HD2 + d0;
    const float4 q0 = *(const float4*)(row + 0);
    const float4 q1 = *(const float4*)(row + 4);
    const float4 q2 = *(const float4*)(row + 8);
    const float4 q3 = *(const float4*)(row + 12);
    a[0]  += wt * q0.x; a[1]  += wt * q0.y; a[2]  += wt * q0.z; a[3]  += wt * q0.w;
    a[4]  += wt * q1.x; a[5]  += wt * q1.y; a[6]  += wt * q1.z; a[7]  += wt * q1.w;
    a[8]  += wt * q2.x; a[9]  += wt * q2.y; a[10] += wt * q2.z; a[11] += wt * q2.w;
    a[12] += wt * q3.x; a[13] += wt * q3.y; a[14] += wt * q3.z; a[15] += wt * q3.w;
  }
#pragma unroll
  for (int j = 0; j < 16; ++j) cs[w][d0 + j] = a[j];
  __syncthreads();
#pragma unroll
  for (int j = 0; j < 4; ++j) {
    const int d = tid * 4 + j;
    atomicAdd(&context[(size_t)b * HD2 + d],
              cs[0][d] + cs[1][d] + cs[2][d] + cs[3][d]);
  }
}

// ---------- build cat1 / xbuf ----------
__global__ __launch_bounds__(256) void k_cat1(
    const float* __restrict__ context, const float* __restrict__ embed,
    const int* __restrict__ iidx, const float* __restrict__ selread,
    float* __restrict__ cat1, float* __restrict__ xbuf)
{
  const int b = blockIdx.x;
  const int tid = threadIdx.x;
  for (int d = tid; d < HD2; d += 256) {
    cat1[(size_t)b * 1280 + d] = context[(size_t)b * HD2 + d];
    xbuf[(size_t)b * G3 + 512 + d] = selread[(size_t)b * HD2 + d];
  }
  int ei = iidx[b];
  if (ei >= VV) ei = 2;
  cat1[(size_t)b * 1280 + 1024 + tid] = embed[(size_t)ei * EE + tid];
}

// ---------- GRU cell ----------
__global__ __launch_bounds__(256) void k_gru(
    const float* __restrict__ gi, const float* __restrict__ gh,
    const float* __restrict__ ps, float* __restrict__ st)
{
  const int t = blockIdx.x * 256 + threadIdx.x;
  const int b = t >> 9, h = t & 511;
  const float* gib = gi + (size_t)b * G3;
  const float* ghb = gh + (size_t)b * G3;
  const float r = fsigmoid(gib[h] + ghb[h]);
  const float z = fsigmoid(gib[512 + h] + ghb[512 + h]);
  const float n = ftanh(gib[1024 + h] + r * ghb[1024 + h]);
  st[t] = (1.f - z) * n + z * ps[t];
}

// ---------- score_g = state @ W_o^T + b_o  (64 x 32000, K=512) ----------
// tile 64x128; micro 4x8 (acc32+a16+w32=80 VGPR, no spill); grid 250.
__global__ __launch_bounds__(256) void k_score_g(
    const float* __restrict__ st, const float* __restrict__ Wo,
    const float* __restrict__ bo, float* __restrict__ sg)
{
  __shared__ float Ss[64][36];
  __shared__ float Ws[128][36];
  const int tid = threadIdx.x;
  const int n0 = blockIdx.x * 128;
  const int tb = tid & 15;   // rows tb+16i (i<4)
  const int tn = tid >> 4;   // cols tn+16j (j<8)
  float acc[4][8];
#pragma unroll
  for (int i = 0; i < 4; ++i)
#pragma unroll
    for (int j = 0; j < 8; ++j) acc[i][j] = 0.f;

  const int rr = tid >> 3;
  const int cc = (tid & 7) * 4;
  for (int kc = 0; kc < 512; kc += 32) {
    __syncthreads();
#pragma unroll
    for (int r = rr; r < 64; r += 32)
      *(float4*)&Ss[r][cc] = *(const float4*)&st[(size_t)r * 512 + kc + cc];
#pragma unroll
    for (int r = rr; r < 128; r += 32)
      *(float4*)&Ws[r][cc] = *(const float4*)&Wo[(size_t)(n0 + r) * 512 + kc + cc];
    __syncthreads();
#pragma unroll
    for (int k4 = 0; k4 < 32; k4 += 4) {
      float4 a[4], w[8];
#pragma unroll
      for (int i = 0; i < 4; ++i) a[i] = *(const float4*)&Ss[tb + 16*i][k4];
#pragma unroll
      for (int j = 0; j < 8; ++j) w[j] = *(const float4*)&Ws[tn + 16*j][k4];
#pragma unroll
      for (int i = 0; i < 4; ++i)
#pragma unroll
        for (int j = 0; j < 8; ++j)
          acc[i][j] += dot4(a[i], w[j]);
    }
  }
#pragma unroll
  for (int i = 0; i < 4; ++i)
#pragma unroll
    for (int j = 0; j < 8; ++j)
      sg[(size_t)(tb + 16*i) * VV + n0 + tn + 16*j] = acc[i][j] + bo[n0 + tn + 16*j];
}

// ---------- fused score_c via MFMA (bf16 3-mult split) ----------
// scc[b,s] = sum_h tanh(enc[b,s,:]@Wc[h,:]+bc[h]) * state[b,h]
// GEMM M=16384 N=512 K=1024; tile 128x128, 4 waves, 4x4 16x16x32 frags/wave.
// A (enc fp32) split hi/lo on the fly; B (Wc) pre-split. XOR-swizzled LDS.
__global__ __launch_bounds__(256) void k_score_c(
    const float* __restrict__ enc,
    const ushort* __restrict__ whi, const ushort* __restrict__ wlo,
    const float* __restrict__ bc, const float* __restrict__ st,
    float* __restrict__ scc)
{
  __shared__ ushort sAhi[128 * 32];
  __shared__ ushort sAlo[128 * 32];
  __shared__ ushort sBhi[128 * 32];
  __shared__ ushort sBlo[128 * 32];

  const int tid = threadIdx.x;
  const int m0 = blockIdx.x * 128;      // enc row (b*256 + s)
  const int n0 = blockIdx.y * 128;      // h offset
  const int b  = m0 >> 8;
  const int lane = tid & 63;
  const int wid = tid >> 6;
  const int wr = wid >> 1, wc = wid & 1;   // wave tile 64x64
  const int kg = lane >> 4;                // k-group 0..3
  const int rl = lane & 15;

  f32x4 acc[4][4];
#pragma unroll
  for (int m = 0; m < 4; ++m)
#pragma unroll
    for (int n = 0; n < 4; ++n) acc[m][n] = (f32x4){0.f, 0.f, 0.f, 0.f};

  const int ar = tid >> 3;          // A stage: row base 0..31
  const int ak = (tid & 7) * 4;     // A stage: k0
  const int br = tid >> 2;          // B stage: row base 0..63
  const int bs = tid & 3;           // B stage: 16B slot

  for (int kc = 0; kc < 1024; kc += 32) {
    __syncthreads();
    // ---- stage A (fp32 -> hi/lo bf16, swizzled) ----
#pragma unroll
    for (int swp = 0; swp < 4; ++swp) {
      const int row = ar + swp * 32;
      const float4 v = *(const float4*)&enc[(size_t)(m0 + row) * 1024 + kc + ak];
      ushort4 h, l;
      split2(v.x, h.x, l.x); split2(v.y, h.y, l.y);
      split2(v.z, h.z, l.z); split2(v.w, h.w, l.w);
      const int sw = (row + (row >> 2)) & 3;
      const int off = row * 64 + (((ak >> 3) ^ sw) * 16) + (ak & 7) * 2;
      *(ushort4*)((char*)sAhi + off) = h;
      *(ushort4*)((char*)sAlo + off) = l;
    }
    // ---- stage B (pre-split bf16, swizzled) ----
#pragma unroll
    for (int swp = 0; swp < 2; ++swp) {
      const int row = br + swp * 64;
      const size_t g = (size_t)(n0 + row) * 1024 + kc + bs * 8;
      const uint4 hv = *(const uint4*)&whi[g];
      const uint4 lv = *(const uint4*)&wlo[g];
      const int sw = (row + (row >> 2)) & 3;
      const int off = row * 64 + ((bs ^ sw) * 16);
      *(uint4*)((char*)sBhi + off) = hv;
      *(uint4*)((char*)sBlo + off) = lv;
    }
    __syncthreads();
    // ---- fragments + MFMA ----
    bhalf8 ahi[4], alo[4], bhi[4], blo[4];
#pragma unroll
    for (int m = 0; m < 4; ++m) {
      const int row = wr * 64 + m * 16 + rl;
      const int off = row * 64 + ((kg ^ ((row + (row >> 2)) & 3)) * 16);
      ahi[m] = *(const bhalf8*)((const char*)sAhi + off);
      alo[m] = *(const bhalf8*)((const char*)sAlo + off);
    }
#pragma unroll
    for (int n = 0; n < 4; ++n) {
      const int row = wc * 64 + n * 16 + rl;
      const int off = row * 64 + ((kg ^ ((row + (row >> 2)) & 3)) * 16);
      bhi[n] = *(const bhalf8*)((const char*)sBhi + off);
      blo[n] = *(const bhalf8*)((const char*)sBlo + off);
    }
#pragma unroll
    for (int m = 0; m < 4; ++m)
#pragma unroll
      for (int n = 0; n < 4; ++n) {
        acc[m][n] = __builtin_amdgcn_mfma_f32_16x16x32_bf16(ahi[m], bhi[n], acc[m][n], 0, 0, 0);
        acc[m][n] = __builtin_amdgcn_mfma_f32_16x16x32_bf16(ahi[m], blo[n], acc[m][n], 0, 0, 0);
        acc[m][n] = __builtin_amdgcn_mfma_f32_16x16x32_bf16(alo[m], bhi[n], acc[m][n], 0, 0, 0);
      }
  }

  // ---- epilogue: tanh(acc + bc)*state, reduce over h, atomicAdd to scc ----
  float bcv[4], stv[4];
#pragma unroll
  for (int n = 0; n < 4; ++n) {
    const int col = n0 + wc * 64 + n * 16 + rl;
    bcv[n] = bc[col];
    stv[n] = st[(size_t)b * 512 + col];
  }
  float rs[4][4];
#pragma unroll
  for (int m = 0; m < 4; ++m)
#pragma unroll
    for (int r = 0; r < 4; ++r) {
      float p = 0.f;
#pragma unroll
      for (int n = 0; n < 4; ++n)
        p += ftanh(acc[m][n][r] + bcv[n]) * stv[n];
      rs[m][r] = p;
    }
#pragma unroll
  for (int off = 1; off < 16; off <<= 1)
#pragma unroll
    for (int m = 0; m < 4; ++m)
#pragma unroll
      for (int r = 0; r < 4; ++r)
        rs[m][r] += __shfl_xor(rs[m][r], off);
  if (rl == 0) {
#pragma unroll
    for (int m = 0; m < 4; ++m)
#pragma unroll
      for (int r = 0; r < 4; ++r) {
        const int srow = (m0 & 255) + wr * 64 + m * 16 + kg * 4 + r;
        atomicAdd(&scc[b * SS + srow], rs[m][r]);
      }
  }
}

// ---------- softmax over [score_g | score_c] ----------
__global__ __launch_bounds__(1024) void k_bigsoftmax(
    const float* __restrict__ sg, const float* __restrict__ scc,
    float* __restrict__ out, float* __restrict__ pc0, float* __restrict__ stats)
{
  const int b = blockIdx.x;
  const int tid = threadIdx.x;
  const int lane = tid & 63, w = tid >> 6;
  __shared__ float red[16];
  __shared__ float bm, bsum;
  const float* sgb = sg + (size_t)b * VV;
  const float* scb = scc + (size_t)b * SS;

  float m = -3.0e38f;
  for (int v = tid; v < VV; v += 1024) m = fmaxf(m, sgb[v]);
  if (tid < SS) m = fmaxf(m, scb[tid]);
  m = wredmax(m);
  if (lane == 0) red[w] = m;
  __syncthreads();
  if (tid == 0) {
    float t = red[0];
    for (int i = 1; i < 16; ++i) t = fmaxf(t, red[i]);
    bm = t;
  }
  __syncthreads();
  const float mx = bm;

  float s = 0.f;
  for (int v = tid; v < VV; v += 1024) s += __expf(sgb[v] - mx);
  if (tid < SS) s += __expf(scb[tid] - mx);
  s = wredsum(s);
  if (lane == 0) red[w] = s;
  __syncthreads();
  if (tid == 0) {
    float t = 0.f;
    for (int i = 0; i < 16; ++i) t += red[i];
    bsum = t;
  }
  __syncthreads();
  const float inv = 1.f / bsum;
  if (tid == 0) { stats[2*b] = mx; stats[2*b + 1] = inv; }

  float* outb = out + (size_t)b * MLSZ;
  for (int v = tid; v < VV; v += 1024) outb[v] = __expf(sgb[v] - mx) * inv;
  if (tid < SS) {
    pc0[b * SS + tid] = __expf(scb[tid] - mx) * inv;
    outb[VV + tid] = 0.f;
  }
}

// ---------- prob_c ----------
__global__ __launch_bounds__(256) void k_probc(
    const int* __restrict__ seq, const float* __restrict__ pc0,
    float* __restrict__ pcout)
{
  const int b = blockIdx.x;
  const int tid = threadIdx.x;
  __shared__ int sq[256];
  __shared__ float pp[256];
  sq[tid] = seq[b * SS + tid];
  pp[tid] = pc0[b * SS + tid];
  __syncthreads();
  const int mys = sq[tid];
  float acc = 0.f;
  for (int i = 0; i < 256; ++i) acc += (sq[i] == mys) ? pp[i] : 0.f;
  pcout[b * SS + tid] = acc;
}

// ---------- scatter ----------
__global__ __launch_bounds__(256) void k_scatter(
    const int* __restrict__ seq, const float* __restrict__ pcout,
    const float* __restrict__ sg, const float* __restrict__ stats,
    float* __restrict__ out)
{
  const int b = blockIdx.x;
  const int tid = threadIdx.x;
  const int v = seq[b * SS + tid];
  if (v < 0 || v >= MLSZ) return;
  float val = pcout[b * SS + tid];
  if (v < VV) val += __expf(sg[(size_t)b * VV + v] - stats[2*b]) * stats[2*b + 1];
  out[(size_t)b * MLSZ + v] = val;
}

// ---------- launch ----------
extern "C" void kernel_launch(void* const* d_in, const int* in_sizes, int n_in,
                              void* d_out, int out_size, void* d_ws, size_t ws_size,
                              hipStream_t stream)
{
  (void)in_sizes; (void)n_in; (void)out_size; (void)ws_size;
  const int*   input_idx = (const int*)d_in[0];
  const float* enc       = (const float*)d_in[1];
  const int*   seq       = (const int*)d_in[2];
  const float* pre_state = (const float*)d_in[3];
  const float* ppc       = (const float*)d_in[4];
  const float* embed     = (const float*)d_in[5];
  const float* W_aw = (const float*)d_in[6];  const float* b_aw = (const float*)d_in[7];
  const float* W_ac = (const float*)d_in[8];  const float* b_ac = (const float*)d_in[9];
  const float* W_ih = (const float*)d_in[10]; const float* b_ih = (const float*)d_in[11];
  const float* W_hh = (const float*)d_in[12]; const float* b_hh = (const float*)d_in[13];
  const float* W_o  = (const float*)d_in[14]; const float* b_o  = (const float*)d_in[15];
  const float* W_c  = (const float*)d_in[16]; const float* b_c  = (const float*)d_in[17];

  float* out   = (float*)d_out;
  float* st    = out + (size_t)BB * MLSZ;
  float* pcout = st + BB * HH;

  float* ws      = (float*)d_ws;
  float* astr    = ws;                   // 64*1024
  float* gh      = astr    + 65536;      // 64*1536
  float* xbuf    = gh      + 98304;      // 64*1536
  float* gi      = xbuf    + 98304;      // 64*1536
  float* selread = gi      + 98304;      // 64*1024
  float* context = selread + 65536;      // 64*1024
  float* scc     = context + 65536;      // 64*256
  const size_t zlen = 65536 + 98304 + 98304 + 98304 + 65536 + 65536 + 16384; // 507904
  float* scores  = scc     + 16384;
  float* cat1    = scores  + 16384;      // 64*1280
  float* sg      = cat1    + 81920;      // 64*32000
  float* pc0     = sg      + 2048000;    // 64*256
  float* stats   = pc0     + 16384;      // 128
  ushort* whi    = (ushort*)(stats + 128);   // 512*1024 bf16
  ushort* wlo    = whi + 524288;             // 512*1024 bf16

  hipMemsetAsync(ws, 0, zlen * sizeof(float), stream);

  // pre-split W_c into bf16 hi/lo (524288 elems / 4 per thread / 256)
  k_split<<<512, 256, 0, stream>>>(W_c, whi, wlo);

  k_smallgemm<<<dim3(16, 2), 256, 0, stream>>>(pre_state, 512, W_aw, 512, b_aw, astr, 1024, 256);
  k_smallgemm<<<dim3(24, 2), 256, 0, stream>>>(pre_state, 512, W_hh, 512, b_hh, gh, 1536, 256);
  k_pass1<<<256, 256, 0, stream>>>(enc, astr, seq, input_idx, ppc, scores, selread);
  k_softmax_s<<<64, 256, 0, stream>>>(scores);
  k_pass2<<<256, 256, 0, stream>>>(enc, scores, context);
  k_cat1<<<64, 256, 0, stream>>>(context, embed, input_idx, selread, cat1, xbuf);
  k_smallgemm<<<dim3(8, 2), 256, 0, stream>>>(cat1, 1280, W_ac, 1280, b_ac, xbuf, 1536, 640);
  k_smallgemm<<<dim3(24, 4), 256, 0, stream>>>(xbuf, 1536, W_ih, 1536, b_ih, gi, 1536, 384);
  k_gru<<<128, 256, 0, stream>>>(gi, gh, pre_state, st);
  k_score_g<<<250, 256, 0, stream>>>(st, W_o, b_o, sg);
  k_score_c<<<dim3(128, 4), 256, 0, stream>>>(enc, whi, wlo, b_c, st, scc);
  k_bigsoftmax<<<64, 1024, 0, stream>>>(sg, scc, out, pc0, stats);
  k_probc<<<64, 256, 0, stream>>>(seq, pc0, pcout);
  k_scatter<<<64, 256, 0, stream>>>(seq, pcout, sg, stats, out);
}

// Round 3
// 478.957 us; speedup vs baseline: 12.1312x; 1.1332x over previous
//
#include <hip/hip_runtime.h>
#include <hip/hip_bf16.h>
#include <math.h>

#define BB   64
#define SS   256
#define HH   512
#define HD2  1024   // 2H
#define EE   256
#define VV   32000
#define MLSZ 32256
#define G3   1536   // 3H

typedef __attribute__((ext_vector_type(8))) short bhalf8;
typedef __attribute__((ext_vector_type(4))) float f32x4;

// ---------- helpers ----------
__device__ __forceinline__ float wredsum(float v) {
#pragma unroll
  for (int o = 32; o > 0; o >>= 1) v += __shfl_down(v, o);
  return v;
}
__device__ __forceinline__ float wredmax(float v) {
#pragma unroll
  for (int o = 32; o > 0; o >>= 1) v = fmaxf(v, __shfl_down(v, o));
  return v;
}
__device__ __forceinline__ float ftanh(float x) {
  float e = __expf(-2.f * fabsf(x));
  float t = (1.f - e) / (1.f + e);
  return copysignf(t, x);
}
__device__ __forceinline__ float fsigmoid(float x) { return 1.f / (1.f + __expf(-x)); }
__device__ __forceinline__ float dot4(float4 a, float4 b) {
  return a.x*b.x + a.y*b.y + a.z*b.z + a.w*b.w;
}
// fp32 -> bf16 RNE
__device__ __forceinline__ ushort bf16rne(float x) {
  uint u = __float_as_uint(x);
  return (ushort)((u + 0x7fffu + ((u >> 16) & 1u)) >> 16);
}
// fp32 -> bf16 hi/lo split (RNE both): x ~= hi + lo to ~2^-18 rel
__device__ __forceinline__ void split2(float x, ushort& h, ushort& l) {
  uint u = __float_as_uint(x);
  uint hr = (u + 0x7fffu + ((u >> 16) & 1u)) & 0xffff0000u;
  h = (ushort)(hr >> 16);
  float r = x - __uint_as_float(hr);
  uint u2 = __float_as_uint(r);
  l = (ushort)((u2 + 0x7fffu + ((u2 >> 16) & 1u)) >> 16);
}

// ---------- W_c -> fragment-ordered bf16 hi/lo ----------
// elem (col,k) -> lane=((k>>3)&3)*16+(col&15), j=k&7, buf[((nf*32+kc)*64+lane)*8+j]
__global__ __launch_bounds__(256) void k_split_wc(
    const float* __restrict__ Wc, ushort* __restrict__ bhi, ushort* __restrict__ blo)
{
  const int tid = blockIdx.x * 256 + threadIdx.x;  // 65536
  const int col = tid >> 7;        // 0..511
  const int g   = tid & 127;       // k-group of 8
  const float* p = Wc + (size_t)col * 1024 + g * 8;
  const float4 v0 = *(const float4*)p;
  const float4 v1 = *(const float4*)(p + 4);
  ushort h[8], l[8];
  split2(v0.x, h[0], l[0]); split2(v0.y, h[1], l[1]);
  split2(v0.z, h[2], l[2]); split2(v0.w, h[3], l[3]);
  split2(v1.x, h[4], l[4]); split2(v1.y, h[5], l[5]);
  split2(v1.z, h[6], l[6]); split2(v1.w, h[7], l[7]);
  const int lane = ((g & 3) << 4) | (col & 15);
  const int kc = g >> 2, nf = col >> 4;
  const size_t dst = (((size_t)(nf * 32 + kc)) * 64 + lane) * 8;
  *(ushort4*)&bhi[dst] = make_ushort4(h[0], h[1], h[2], h[3]);
  *(ushort4*)&bhi[dst + 4] = make_ushort4(h[4], h[5], h[6], h[7]);
  *(ushort4*)&blo[dst] = make_ushort4(l[0], l[1], l[2], l[3]);
  *(ushort4*)&blo[dst + 4] = make_ushort4(l[4], l[5], l[6], l[7]);
}

// ---------- state -> fragment-ordered bf16 (hi only) ----------
// buf[((mf*16+kc)*64+lane)*8+j]
__global__ __launch_bounds__(256) void k_split_state(
    const float* __restrict__ st, ushort* __restrict__ ap)
{
  const int tid = blockIdx.x * 256 + threadIdx.x;  // 4096
  const int row = tid >> 6;        // 0..63
  const int g   = tid & 63;        // k-group of 8
  const float* p = st + (size_t)row * 512 + g * 8;
  const float4 v0 = *(const float4*)p;
  const float4 v1 = *(const float4*)(p + 4);
  const int lane = ((g & 3) << 4) | (row & 15);
  const int kc = g >> 2, mf = row >> 4;
  const size_t dst = (((size_t)(mf * 16 + kc)) * 64 + lane) * 8;
  *(ushort4*)&ap[dst] = make_ushort4(bf16rne(v0.x), bf16rne(v0.y), bf16rne(v0.z), bf16rne(v0.w));
  *(ushort4*)&ap[dst + 4] = make_ushort4(bf16rne(v1.x), bf16rne(v1.y), bf16rne(v1.z), bf16rne(v1.w));
}

// ---------- generic small GEMM: C[64,N] = A[64,K] @ W[N,K]^T (+bias), atomic accum ----------
__global__ __launch_bounds__(256) void k_smallgemm(
    const float* __restrict__ A, int lda,
    const float* __restrict__ W, int ldw,
    const float* __restrict__ bias,
    float* __restrict__ C, int ldc, int klen)
{
  __shared__ float As[64][36];
  __shared__ float Ws[64][36];
  const int tid = threadIdx.x;
  const int n0 = blockIdx.x * 64;
  const int kbeg = blockIdx.y * klen;
  const int tb = tid & 15;
  const int tn = tid >> 4;
  float acc[4][4];
#pragma unroll
  for (int i = 0; i < 4; ++i)
#pragma unroll
    for (int j = 0; j < 4; ++j)
      acc[i][j] = (blockIdx.y == 0) ? bias[n0 + tn + 16*j] : 0.f;

  const int rr = tid >> 3;
  const int cc = (tid & 7) * 4;
  for (int kc = kbeg; kc < kbeg + klen; kc += 32) {
    __syncthreads();
#pragma unroll
    for (int r = rr; r < 64; r += 32) {
      *(float4*)&As[r][cc] = *(const float4*)&A[(size_t)r * lda + kc + cc];
      *(float4*)&Ws[r][cc] = *(const float4*)&W[(size_t)(n0 + r) * ldw + kc + cc];
    }
    __syncthreads();
#pragma unroll
    for (int k4 = 0; k4 < 32; k4 += 4) {
      float4 a[4], w[4];
#pragma unroll
      for (int i = 0; i < 4; ++i) a[i] = *(const float4*)&As[tb + 16*i][k4];
#pragma unroll
      for (int j = 0; j < 4; ++j) w[j] = *(const float4*)&Ws[tn + 16*j][k4];
#pragma unroll
      for (int i = 0; i < 4; ++i)
#pragma unroll
        for (int j = 0; j < 4; ++j)
          acc[i][j] += dot4(a[i], w[j]);
    }
  }
#pragma unroll
  for (int i = 0; i < 4; ++i)
#pragma unroll
    for (int j = 0; j < 4; ++j)
      atomicAdd(&C[(size_t)(tb + 16*i) * ldc + n0 + tn + 16*j], acc[i][j]);
}

// ---------- pass1: attn_scores + select_reading ----------
__global__ __launch_bounds__(256) void k_pass1(
    const float* __restrict__ enc, const float* __restrict__ astr,
    const int* __restrict__ seq, const int* __restrict__ iidx,
    const float* __restrict__ ppc,
    float* __restrict__ scores, float* __restrict__ selread)
{
  const int b  = blockIdx.x >> 2;
  const int sc = blockIdx.x & 3;
  const int tid = threadIdx.x;
  const int lane = tid & 63;
  const int w = tid >> 6;
  __shared__ float sr_s[4][1024];

  const int d0 = lane * 16;
  const float* ap = astr + (size_t)b * HD2 + d0;
  const float4 a0 = *(const float4*)(ap + 0);
  const float4 a1 = *(const float4*)(ap + 4);
  const float4 a2 = *(const float4*)(ap + 8);
  const float4 a3 = *(const float4*)(ap + 12);

  float sr[16];
#pragma unroll
  for (int j = 0; j < 16; ++j) sr[j] = 0.f;

  const int idxb = iidx[b];
  const int sbase = sc * 64 + w * 16;
  for (int si = 0; si < 16; ++si) {
    const int s = sbase + si;
    const float* row = enc + ((size_t)b * SS + s) * HD2 + d0;
    const float4 q0 = *(const float4*)(row + 0);
    const float4 q1 = *(const float4*)(row + 4);
    const float4 q2 = *(const float4*)(row + 8);
    const float4 q3 = *(const float4*)(row + 12);
    float dot = dot4(q0, a0) + dot4(q1, a1) + dot4(q2, a2) + dot4(q3, a3);
    dot = wredsum(dot);
    if (lane == 0) scores[b * SS + s] = dot;
    const float sw = (seq[b * SS + s] == idxb) ? ppc[b * SS + s] : 0.f;
    if (sw != 0.f) {
      sr[0]  += sw * q0.x; sr[1]  += sw * q0.y; sr[2]  += sw * q0.z; sr[3]  += sw * q0.w;
      sr[4]  += sw * q1.x; sr[5]  += sw * q1.y; sr[6]  += sw * q1.z; sr[7]  += sw * q1.w;
      sr[8]  += sw * q2.x; sr[9]  += sw * q2.y; sr[10] += sw * q2.z; sr[11] += sw * q2.w;
      sr[12] += sw * q3.x; sr[13] += sw * q3.y; sr[14] += sw * q3.z; sr[15] += sw * q3.w;
    }
  }
#pragma unroll
  for (int j = 0; j < 16; ++j) sr_s[w][d0 + j] = sr[j];
  __syncthreads();
#pragma unroll
  for (int j = 0; j < 4; ++j) {
    const int d = tid * 4 + j;
    const float v = sr_s[0][d] + sr_s[1][d] + sr_s[2][d] + sr_s[3][d];
    atomicAdd(&selread[(size_t)b * HD2 + d], v);
  }
}

// ---------- softmax over S per row ----------
__global__ __launch_bounds__(256) void k_softmax_s(float* __restrict__ scores)
{
  const int b = blockIdx.x;
  const int tid = threadIdx.x;
  const int lane = tid & 63, w = tid >> 6;
  __shared__ float red[4];
  __shared__ float bm, bsum;
  float x = scores[b * SS + tid];
  float m = wredmax(x);
  if (lane == 0) red[w] = m;
  __syncthreads();
  if (tid == 0) bm = fmaxf(fmaxf(red[0], red[1]), fmaxf(red[2], red[3]));
  __syncthreads();
  float e = __expf(x - bm);
  float s = wredsum(e);
  if (lane == 0) red[w] = s;
  __syncthreads();
  if (tid == 0) bsum = red[0] + red[1] + red[2] + red[3];
  __syncthreads();
  scores[b * SS + tid] = e / bsum;
}

// ---------- pass2: context ----------
__global__ __launch_bounds__(256) void k_pass2(
    const float* __restrict__ enc, const float* __restrict__ wgt,
    float* __restrict__ context)
{
  const int b  = blockIdx.x >> 2;
  const int sc = blockIdx.x & 3;
  const int tid = threadIdx.x;
  const int lane = tid & 63;
  const int w = tid >> 6;
  __shared__ float cs[4][1024];
  const int d0 = lane * 16;
  float a[16];
#pragma unroll
  for (int j = 0; j < 16; ++j) a[j] = 0.f;
  const int sbase = sc * 64 + w * 16;
  for (int si = 0; si < 16; ++si) {
    const int s = sbase + si;
    const float wt = wgt[b * SS + s];
    const float* row = enc + ((size_t)b * SS + s) * HD2 + d0;
    const float4 q0 = *(const float4*)(row + 0);
    const float4 q1 = *(const float4*)(row + 4);
    const float4 q2 = *(const float4*)(row + 8);
    const float4 q3 = *(const float4*)(row + 12);
    a[0]  += wt * q0.x; a[1]  += wt * q0.y; a[2]  += wt * q0.z; a[3]  += wt * q0.w;
    a[4]  += wt * q1.x; a[5]  += wt * q1.y; a[6]  += wt * q1.z; a[7]  += wt * q1.w;
    a[8]  += wt * q2.x; a[9]  += wt * q2.y; a[10] += wt * q2.z; a[11] += wt * q2.w;
    a[12] += wt * q3.x; a[13] += wt * q3.y; a[14] += wt * q3.z; a[15] += wt * q3.w;
  }
#pragma unroll
  for (int j = 0; j < 16; ++j) cs[w][d0 + j] = a[j];
  __syncthreads();
#pragma unroll
  for (int j = 0; j < 4; ++j) {
    const int d = tid * 4 + j;
    atomicAdd(&context[(size_t)b * HD2 + d],
              cs[0][d] + cs[1][d] + cs[2][d] + cs[3][d]);
  }
}

// ---------- build cat1 / xbuf ----------
__global__ __launch_bounds__(256) void k_cat1(
    const float* __restrict__ context, const float* __restrict__ embed,
    const int* __restrict__ iidx, const float* __restrict__ selread,
    float* __restrict__ cat1, float* __restrict__ xbuf)
{
  const int b = blockIdx.x;
  const int tid = threadIdx.x;
  for (int d = tid; d < HD2; d += 256) {
    cat1[(size_t)b * 1280 + d] = context[(size_t)b * HD2 + d];
    xbuf[(size_t)b * G3 + 512 + d] = selread[(size_t)b * HD2 + d];
  }
  int ei = iidx[b];
  if (ei >= VV) ei = 2;
  cat1[(size_t)b * 1280 + 1024 + tid] = embed[(size_t)ei * EE + tid];
}

// ---------- GRU cell ----------
__global__ __launch_bounds__(256) void k_gru(
    const float* __restrict__ gi, const float* __restrict__ gh,
    const float* __restrict__ ps, float* __restrict__ st)
{
  const int t = blockIdx.x * 256 + threadIdx.x;
  const int b = t >> 9, h = t & 511;
  const float* gib = gi + (size_t)b * G3;
  const float* ghb = gh + (size_t)b * G3;
  const float r = fsigmoid(gib[h] + ghb[h]);
  const float z = fsigmoid(gib[512 + h] + ghb[512 + h]);
  const float n = ftanh(gib[1024 + h] + r * ghb[1024 + h]);
  st[t] = (1.f - z) * n + z * ps[t];
}

// ---------- score_g: bf16-MFMA streamer, no LDS, no barriers ----------
// sg[b, n] = state[b,:] @ Wo[n,:] + bo[n]. Grid 500 (n-tile 64), 4 waves (n-frag each).
__global__ __launch_bounds__(256) void k_score_g(
    const ushort* __restrict__ ap, const float* __restrict__ Wo,
    const float* __restrict__ bo, float* __restrict__ sg)
{
  const int tid = threadIdx.x;
  const int lane = tid & 63;
  const int wid = tid >> 6;              // n-frag 0..3
  const int rl = lane & 15, kg = lane >> 4;
  const int n0 = blockIdx.x * 64;
  const int col = n0 + wid * 16 + rl;
  const float* wrow = Wo + (size_t)col * 512 + kg * 8;

  f32x4 acc[4];
#pragma unroll
  for (int m = 0; m < 4; ++m) acc[m] = (f32x4){0.f, 0.f, 0.f, 0.f};

#pragma unroll 4
  for (int kc = 0; kc < 16; ++kc) {
    const float4 w0 = *(const float4*)(wrow + kc * 32);
    const float4 w1 = *(const float4*)(wrow + kc * 32 + 4);
    bhalf8 bh;
    bh[0] = (short)bf16rne(w0.x); bh[1] = (short)bf16rne(w0.y);
    bh[2] = (short)bf16rne(w0.z); bh[3] = (short)bf16rne(w0.w);
    bh[4] = (short)bf16rne(w1.x); bh[5] = (short)bf16rne(w1.y);
    bh[6] = (short)bf16rne(w1.z); bh[7] = (short)bf16rne(w1.w);
#pragma unroll
    for (int m = 0; m < 4; ++m) {
      const bhalf8 a = *(const bhalf8*)(ap + (((size_t)(m * 16 + kc)) * 64 + lane) * 8);
      acc[m] = __builtin_amdgcn_mfma_f32_16x16x32_bf16(a, bh, acc[m], 0, 0, 0);
    }
  }
  const float bv = bo[col];
#pragma unroll
  for (int m = 0; m < 4; ++m)
#pragma unroll
    for (int r = 0; r < 4; ++r)
      sg[(size_t)(m * 16 + kg * 4 + r) * VV + col] = acc[m][r] + bv;
}

// ---------- fused score_c via MFMA (3-mult bf16 split), enc read ONCE ----------
// Grid 256 (m-tile 64 enc rows), 512 thr = 8 waves; wave owns 4 n-frags (64 cols), all M.
__global__ __launch_bounds__(512) void k_score_c(
    const float* __restrict__ enc,
    const ushort* __restrict__ wfh, const ushort* __restrict__ wfl,
    const float* __restrict__ bc, const float* __restrict__ st,
    float* __restrict__ scc)
{
  __shared__ ushort sAhi[64 * 32];
  __shared__ ushort sAlo[64 * 32];
  const int tid = threadIdx.x;
  const int lane = tid & 63;
  const int wid = tid >> 6;            // 0..7
  const int rl = lane & 15, kg = lane >> 4;
  const int m0 = blockIdx.x * 64;
  const int b = m0 >> 8;

  // staging coords: thread stages one float4 of the 64x32 A-chunk
  const int srow = tid >> 3;
  const int skq = (tid & 7) * 4;
  const int ssw = (srow + (srow >> 2)) & 3;
  const int soff = srow * 64 + (((skq >> 3) ^ ssw) * 16) + (skq & 7) * 2;
  const float* aseg = enc + (size_t)(m0 + srow) * 1024 + skq;

  f32x4 acc[4][4];
#pragma unroll
  for (int m = 0; m < 4; ++m)
#pragma unroll
    for (int n = 0; n < 4; ++n) acc[m][n] = (f32x4){0.f, 0.f, 0.f, 0.f};

  for (int kc = 0; kc < 32; ++kc) {
    __syncthreads();
    const float4 v = *(const float4*)(aseg + kc * 32);
    ushort4 h, l;
    split2(v.x, h.x, l.x); split2(v.y, h.y, l.y);
    split2(v.z, h.z, l.z); split2(v.w, h.w, l.w);
    *(ushort4*)((char*)sAhi + soff) = h;
    *(ushort4*)((char*)sAlo + soff) = l;
    // B frags (global, L2-hot, coalesced 16B/lane)
    bhalf8 bhi[4], blo[4];
#pragma unroll
    for (int n = 0; n < 4; ++n) {
      const size_t src = (((size_t)((wid * 4 + n) * 32 + kc)) * 64 + lane) * 8;
      bhi[n] = *(const bhalf8*)(wfh + src);
      blo[n] = *(const bhalf8*)(wfl + src);
    }
    __syncthreads();
    bhalf8 ahi[4], alo[4];
#pragma unroll
    for (int m = 0; m < 4; ++m) {
      const int row = m * 16 + rl;
      const int off = row * 64 + ((kg ^ ((row + (row >> 2)) & 3)) * 16);
      ahi[m] = *(const bhalf8*)((const char*)sAhi + off);
      alo[m] = *(const bhalf8*)((const char*)sAlo + off);
    }
#pragma unroll
    for (int m = 0; m < 4; ++m)
#pragma unroll
      for (int n = 0; n < 4; ++n) {
        acc[m][n] = __builtin_amdgcn_mfma_f32_16x16x32_bf16(ahi[m], bhi[n], acc[m][n], 0, 0, 0);
        acc[m][n] = __builtin_amdgcn_mfma_f32_16x16x32_bf16(ahi[m], blo[n], acc[m][n], 0, 0, 0);
        acc[m][n] = __builtin_amdgcn_mfma_f32_16x16x32_bf16(alo[m], bhi[n], acc[m][n], 0, 0, 0);
      }
  }

  // epilogue: tanh(acc+bc)*state, reduce over this wave's 64 cols, atomic into scc
  float bcv[4], stv[4];
#pragma unroll
  for (int n = 0; n < 4; ++n) {
    const int c = (wid * 4 + n) * 16 + rl;
    bcv[n] = bc[c];
    stv[n] = st[(size_t)b * 512 + c];
  }
  float rs[4][4];
#pragma unroll
  for (int m = 0; m < 4; ++m)
#pragma unroll
    for (int r = 0; r < 4; ++r) {
      float p = 0.f;
#pragma unroll
      for (int n = 0; n < 4; ++n)
        p += ftanh(acc[m][n][r] + bcv[n]) * stv[n];
      rs[m][r] = p;
    }
#pragma unroll
  for (int off = 1; off < 16; off <<= 1)
#pragma unroll
    for (int m = 0; m < 4; ++m)
#pragma unroll
      for (int r = 0; r < 4; ++r)
        rs[m][r] += __shfl_xor(rs[m][r], off);
  if (rl == 0) {
#pragma unroll
    for (int m = 0; m < 4; ++m)
#pragma unroll
      for (int r = 0; r < 4; ++r)
        atomicAdd(&scc[b * SS + (m0 & 255) + m * 16 + kg * 4 + r], rs[m][r]);
  }
}

// ---------- softmax over [score_g | score_c] ----------
__global__ __launch_bounds__(1024) void k_bigsoftmax(
    const float* __restrict__ sg, const float* __restrict__ scc,
    float* __restrict__ out, float* __restrict__ pc0, float* __restrict__ stats)
{
  const int b = blockIdx.x;
  const int tid = threadIdx.x;
  const int lane = tid & 63, w = tid >> 6;
  __shared__ float red[16];
  __shared__ float bm, bsum;
  const float* sgb = sg + (size_t)b * VV;
  const float* scb = scc + (size_t)b * SS;

  float m = -3.0e38f;
  for (int v = tid; v < VV; v += 1024) m = fmaxf(m, sgb[v]);
  if (tid < SS) m = fmaxf(m, scb[tid]);
  m = wredmax(m);
  if (lane == 0) red[w] = m;
  __syncthreads();
  if (tid == 0) {
    float t = red[0];
    for (int i = 1; i < 16; ++i) t = fmaxf(t, red[i]);
    bm = t;
  }
  __syncthreads();
  const float mx = bm;

  float s = 0.f;
  for (int v = tid; v < VV; v += 1024) s += __expf(sgb[v] - mx);
  if (tid < SS) s += __expf(scb[tid] - mx);
  s = wredsum(s);
  if (lane == 0) red[w] = s;
  __syncthreads();
  if (tid == 0) {
    float t = 0.f;
    for (int i = 0; i < 16; ++i) t += red[i];
    bsum = t;
  }
  __syncthreads();
  const float inv = 1.f / bsum;
  if (tid == 0) { stats[2*b] = mx; stats[2*b + 1] = inv; }

  float* outb = out + (size_t)b * MLSZ;
  for (int v = tid; v < VV; v += 1024) outb[v] = __expf(sgb[v] - mx) * inv;
  if (tid < SS) {
    pc0[b * SS + tid] = __expf(scb[tid] - mx) * inv;
    outb[VV + tid] = 0.f;
  }
}

// ---------- prob_c ----------
__global__ __launch_bounds__(256) void k_probc(
    const int* __restrict__ seq, const float* __restrict__ pc0,
    float* __restrict__ pcout)
{
  const int b = blockIdx.x;
  const int tid = threadIdx.x;
  __shared__ int sq[256];
  __shared__ float pp[256];
  sq[tid] = seq[b * SS + tid];
  pp[tid] = pc0[b * SS + tid];
  __syncthreads();
  const int mys = sq[tid];
  float acc = 0.f;
  for (int i = 0; i < 256; ++i) acc += (sq[i] == mys) ? pp[i] : 0.f;
  pcout[b * SS + tid] = acc;
}

// ---------- scatter ----------
__global__ __launch_bounds__(256) void k_scatter(
    const int* __restrict__ seq, const float* __restrict__ pcout,
    const float* __restrict__ sg, const float* __restrict__ stats,
    float* __restrict__ out)
{
  const int b = blockIdx.x;
  const int tid = threadIdx.x;
  const int v = seq[b * SS + tid];
  if (v < 0 || v >= MLSZ) return;
  float val = pcout[b * SS + tid];
  if (v < VV) val += __expf(sg[(size_t)b * VV + v] - stats[2*b]) * stats[2*b + 1];
  out[(size_t)b * MLSZ + v] = val;
}

// ---------- launch ----------
extern "C" void kernel_launch(void* const* d_in, const int* in_sizes, int n_in,
                              void* d_out, int out_size, void* d_ws, size_t ws_size,
                              hipStream_t stream)
{
  (void)in_sizes; (void)n_in; (void)out_size; (void)ws_size;
  const int*   input_idx = (const int*)d_in[0];
  const float* enc       = (const float*)d_in[1];
  const int*   seq       = (const int*)d_in[2];
  const float* pre_state = (const float*)d_in[3];
  const float* ppc       = (const float*)d_in[4];
  const float* embed     = (const float*)d_in[5];
  const float* W_aw = (const float*)d_in[6];  const float* b_aw = (const float*)d_in[7];
  const float* W_ac = (const float*)d_in[8];  const float* b_ac = (const float*)d_in[9];
  const float* W_ih = (const float*)d_in[10]; const float* b_ih = (const float*)d_in[11];
  const float* W_hh = (const float*)d_in[12]; const float* b_hh = (const float*)d_in[13];
  const float* W_o  = (const float*)d_in[14]; const float* b_o  = (const float*)d_in[15];
  const float* W_c  = (const float*)d_in[16]; const float* b_c  = (const float*)d_in[17];

  float* out   = (float*)d_out;
  float* st    = out + (size_t)BB * MLSZ;
  float* pcout = st + BB * HH;

  float* ws      = (float*)d_ws;
  float* astr    = ws;                   // 64*1024
  float* gh      = astr    + 65536;      // 64*1536
  float* xbuf    = gh      + 98304;      // 64*1536
  float* gi      = xbuf    + 98304;      // 64*1536
  float* selread = gi      + 98304;      // 64*1024
  float* context = selread + 65536;      // 64*1024
  float* scc     = context + 65536;      // 64*256
  const size_t zlen = 65536 + 98304 + 98304 + 98304 + 65536 + 65536 + 16384; // 507904
  float* scores  = scc     + 16384;
  float* cat1    = scores  + 16384;      // 64*1280
  float* sg      = cat1    + 81920;      // 64*32000
  float* pc0     = sg      + 2048000;    // 64*256
  float* stats   = pc0     + 16384;      // 128
  ushort* wfh    = (ushort*)(stats + 128);   // 512*1024 frag-ordered
  ushort* wfl    = wfh + 524288;
  ushort* stperm = wfl + 524288;             // 64*512 frag-ordered

  hipMemsetAsync(ws, 0, zlen * sizeof(float), stream);

  // W_c -> fragment-ordered bf16 hi/lo (independent of everything else)
  k_split_wc<<<256, 256, 0, stream>>>(W_c, wfh, wfl);

  k_smallgemm<<<dim3(16, 2), 256, 0, stream>>>(pre_state, 512, W_aw, 512, b_aw, astr, 1024, 256);
  k_smallgemm<<<dim3(24, 2), 256, 0, stream>>>(pre_state, 512, W_hh, 512, b_hh, gh, 1536, 256);
  k_pass1<<<256, 256, 0, stream>>>(enc, astr, seq, input_idx, ppc, scores, selread);
  k_softmax_s<<<64, 256, 0, stream>>>(scores);
  k_pass2<<<256, 256, 0, stream>>>(enc, scores, context);
  k_cat1<<<64, 256, 0, stream>>>(context, embed, input_idx, selread, cat1, xbuf);
  k_smallgemm<<<dim3(8, 2), 256, 0, stream>>>(cat1, 1280, W_ac, 1280, b_ac, xbuf, 1536, 640);
  k_smallgemm<<<dim3(24, 4), 256, 0, stream>>>(xbuf, 1536, W_ih, 1536, b_ih, gi, 1536, 384);
  k_gru<<<128, 256, 0, stream>>>(gi, gh, pre_state, st);
  k_split_state<<<16, 256, 0, stream>>>(st, stperm);
  k_score_g<<<500, 256, 0, stream>>>(stperm, W_o, b_o, sg);
  k_score_c<<<256, 512, 0, stream>>>(enc, wfh, wfl, b_c, st, scc);
  k_bigsoftmax<<<64, 1024, 0, stream>>>(sg, scc, out, pc0, stats);
  k_probc<<<64, 256, 0, stream>>>(seq, pc0, pcout);
  k_scatter<<<64, 256, 0, stream>>>(seq, pcout, sg, stats, out);
}